// Round 1
// baseline (359.879 us; speedup 1.0000x reference)
//
#include <hip/hip_runtime.h>

typedef unsigned short u16;
typedef __attribute__((ext_vector_type(8))) short short8;
typedef __attribute__((ext_vector_type(4))) float f32x4;

#define D_TOT 2048
#define M_TOT 64
#define H_TOT 128
#define B_TOT 256
#define XB    131072   /* D_TOT*M_TOT : x row stride per b */
#define W1M   262144   /* H_TOT*D_TOT : w1 stride per m */

__device__ __forceinline__ u16 f2bf(float f) {
  unsigned u = __builtin_bit_cast(unsigned, f);
  u = (u + 0x7fffu + ((u >> 16) & 1u)) >> 16;   // round-to-nearest-even
  return (u16)u;
}
__device__ __forceinline__ float bf2f(u16 v) {
  unsigned u = ((unsigned)v) << 16;
  return __builtin_bit_cast(float, u);
}

// ---------------------------------------------------------------------------
// phase 0: c[h] = b2[h] + sum_d b1[h,d]*w2[h,d]      grid 128 x 256
// ---------------------------------------------------------------------------
__global__ __launch_bounds__(256)
void nlm_p0(const float* __restrict__ b1, const float* __restrict__ w2,
            const float* __restrict__ b2, float* __restrict__ ch) {
  const int h = blockIdx.x, t = threadIdx.x;
  const float4* pb = (const float4*)(b1 + (size_t)h * D_TOT);
  const float4* pw = (const float4*)(w2 + (size_t)h * D_TOT);
  float s = 0.f;
  for (int i = t; i < D_TOT / 4; i += 256) {
    float4 a = pb[i], w = pw[i];
    s += a.x * w.x + a.y * w.y + a.z * w.z + a.w * w.w;
  }
  __shared__ float red[256];
  red[t] = s;
  __syncthreads();
  for (int off = 128; off > 0; off >>= 1) {
    if (t < off) red[t] += red[t + off];
    __syncthreads();
  }
  if (t == 0) ch[h] = red[0] + b2[h];
}

// ---------------------------------------------------------------------------
// phase 1: partial[g][b][h] = sum over d-slice g (8 d's, all 64 m) of
//          x[b,d,m] * (w1[m,h,d]*w2[h,d]), bf16 MFMA, bf16 partial out.
// grid 512 = 256 d-slices x 2 b-halves, block 512 (8 waves as 2x4)
// ---------------------------------------------------------------------------
__global__ __launch_bounds__(512, 4)
void nlm_p1(const float* __restrict__ x, const float* __restrict__ w1,
            const float* __restrict__ w2, u16* __restrict__ partial) {
  // K_local = 512 (k = m_local*8 + d_local), staged in 8 chunks of K=64.
  // A (x side): 128 b x 64 k bf16, row stride 72 (+8 pad: 144B = 36 words ≡ 4 mod 32)
  // B (w1*w2): 128 h x 64 k bf16, same stride.
  __shared__ __align__(16) u16 As[128 * 72];
  __shared__ __align__(16) u16 Bs[128 * 72];

  const int tid  = threadIdx.x;
  const int g    = blockIdx.x >> 1;   // d-slice
  const int bh   = blockIdx.x & 1;    // b-half
  const int d0   = g * 8;
  const int lane = tid & 63, wave = tid >> 6;
  const int wm   = wave >> 2;         // 0..1 : 64-row b tile
  const int wn   = wave & 3;          // 0..3 : 32-col h tile
  const int quad = lane >> 4, l16 = lane & 15;

  // A staging task: thread -> (local b row, m4 in {0,1}, j in {0,4})
  const int a_b  = tid >> 2;
  const int a_r  = tid & 3;
  const int a_m4 = a_r >> 1;
  const int a_j  = (a_r & 1) * 4;
  const float* xbase = x + (size_t)(bh * 128 + a_b) * XB
                         + (size_t)(d0 + a_j) * M_TOT + a_m4 * 4;

  // B staging task: thread -> (h, ml0) ; second task ml0+4, same h
  const int b_h   = tid & 127;
  const int b_ml0 = tid >> 7;         // 0..3
  const float* w2p = w2 + (size_t)b_h * D_TOT + d0;
  const float4 s0 = *(const float4*)(w2p);       // w2[h][d0..d0+4)
  const float4 s1 = *(const float4*)(w2p + 4);   // w2[h][d0+4..d0+8)

  f32x4 acc[4][2];
#pragma unroll
  for (int i = 0; i < 4; ++i)
#pragma unroll
    for (int j = 0; j < 2; ++j) acc[i][j] = (f32x4){0.f, 0.f, 0.f, 0.f};

  for (int c = 0; c < 8; ++c) {       // chunk = 8 m values
    { // ---- stage A: transpose 4d x 4m in registers, write k-contiguous
      const float* xp = xbase + c * 8;
      float4 v0 = *(const float4*)(xp);
      float4 v1 = *(const float4*)(xp + M_TOT);
      float4 v2 = *(const float4*)(xp + 2 * M_TOT);
      float4 v3 = *(const float4*)(xp + 3 * M_TOT);
      u16* ap = As + a_b * 72 + a_m4 * 32 + a_j;  // k = m_l*8 + d_l
      *(ushort4*)(ap)      = make_ushort4(f2bf(v0.x), f2bf(v1.x), f2bf(v2.x), f2bf(v3.x));
      *(ushort4*)(ap + 8)  = make_ushort4(f2bf(v0.y), f2bf(v1.y), f2bf(v2.y), f2bf(v3.y));
      *(ushort4*)(ap + 16) = make_ushort4(f2bf(v0.z), f2bf(v1.z), f2bf(v2.z), f2bf(v3.z));
      *(ushort4*)(ap + 24) = make_ushort4(f2bf(v0.w), f2bf(v1.w), f2bf(v2.w), f2bf(v3.w));
    }
    // ---- stage B: fused w1*w2, contiguous 8-d runs (32B from w1 per pair)
#pragma unroll
    for (int i = 0; i < 2; ++i) {
      const int ml = b_ml0 + i * 4;
      const float* w1p = w1 + (size_t)(c * 8 + ml) * W1M + (size_t)b_h * D_TOT + d0;
      float4 a0 = *(const float4*)(w1p);
      float4 a1 = *(const float4*)(w1p + 4);
      u16* bp = Bs + b_h * 72 + ml * 8;
      *(ushort4*)(bp)     = make_ushort4(f2bf(a0.x * s0.x), f2bf(a0.y * s0.y),
                                         f2bf(a0.z * s0.z), f2bf(a0.w * s0.w));
      *(ushort4*)(bp + 4) = make_ushort4(f2bf(a1.x * s1.x), f2bf(a1.y * s1.y),
                                         f2bf(a1.z * s1.z), f2bf(a1.w * s1.w));
    }
    __syncthreads();
    // ---- compute: 2 K-steps of 32, 8 MFMAs each
#pragma unroll
    for (int s = 0; s < 2; ++s) {
      short8 af[4], bq[2];
#pragma unroll
      for (int i = 0; i < 4; ++i)
        af[i] = *(const short8*)(As + (wm * 64 + i * 16 + l16) * 72 + s * 32 + quad * 8);
#pragma unroll
      for (int j = 0; j < 2; ++j)
        bq[j] = *(const short8*)(Bs + (wn * 32 + j * 16 + l16) * 72 + s * 32 + quad * 8);
#pragma unroll
      for (int i = 0; i < 4; ++i)
#pragma unroll
        for (int j = 0; j < 2; ++j)
          acc[i][j] = __builtin_amdgcn_mfma_f32_16x16x32_bf16(af[i], bq[j], acc[i][j], 0, 0, 0);
    }
    __syncthreads();
  }

  // ---- epilogue: bf16 partials.  C/D layout: col=lane&15, row=quad*4+reg
  u16* pp = partial + (size_t)g * (B_TOT * H_TOT) + (size_t)bh * 128 * H_TOT;
#pragma unroll
  for (int i = 0; i < 4; ++i)
#pragma unroll
    for (int j = 0; j < 2; ++j) {
      const int hcol = wn * 32 + j * 16 + l16;
#pragma unroll
      for (int r = 0; r < 4; ++r) {
        const int brow = wm * 64 + i * 16 + quad * 4 + r;
        pp[brow * H_TOT + hcol] = f2bf(acc[i][j][r]);
      }
    }
}

// ---------------------------------------------------------------------------
// phase 2: out[b,h] = sum_g partial[g][b][h] + c[h]     grid 256 x 256
// ---------------------------------------------------------------------------
__global__ __launch_bounds__(256)
void nlm_p2(const u16* __restrict__ partial, const float* __restrict__ ch,
            float* __restrict__ out) {
  const int b = blockIdx.x, t = threadIdx.x;
  const int h = t & 127, half = t >> 7;
  const u16* p = partial + (size_t)(half * 128) * (B_TOT * H_TOT) + (size_t)b * H_TOT + h;
  float s = 0.f;
#pragma unroll 8
  for (int gg = 0; gg < 128; ++gg) s += bf2f(p[(size_t)gg * (B_TOT * H_TOT)]);
  __shared__ float red[256];
  red[t] = s;
  __syncthreads();
  if (t < 128) out[(size_t)b * H_TOT + t] = red[t] + red[t + 128] + ch[t];
}

// ---------------------------------------------------------------------------
extern "C" void kernel_launch(void* const* d_in, const int* in_sizes, int n_in,
                              void* d_out, int out_size, void* d_ws, size_t ws_size,
                              hipStream_t stream) {
  const float* x  = (const float*)d_in[0];
  const float* w1 = (const float*)d_in[1];
  const float* b1 = (const float*)d_in[2];
  const float* w2 = (const float*)d_in[3];
  const float* b2 = (const float*)d_in[4];
  float* out = (float*)d_out;

  u16*   partial = (u16*)d_ws;                       // 256*256*128 bf16 = 16.78 MB
  float* ch      = (float*)((char*)d_ws + (size_t)256 * B_TOT * H_TOT * sizeof(u16));

  nlm_p0<<<dim3(128), dim3(256), 0, stream>>>(b1, w2, b2, ch);
  nlm_p1<<<dim3(512), dim3(512), 0, stream>>>(x, w1, w2, partial);
  nlm_p2<<<dim3(256), dim3(256), 0, stream>>>(partial, ch, out);
}

// Round 2
// 308.598 us; speedup vs baseline: 1.1662x; 1.1662x over previous
//
#include <hip/hip_runtime.h>

typedef unsigned short u16;
typedef __attribute__((ext_vector_type(8))) short short8;
typedef __attribute__((ext_vector_type(4))) float f32x4;

#define D_TOT 2048
#define M_TOT 64
#define H_TOT 128
#define B_TOT 256
#define NG    256      /* number of d-slices (each 8 d's) */
#define XB    131072   /* D_TOT*M_TOT : x row stride per b */
#define W1M   262144   /* H_TOT*D_TOT : w1 stride per m */

__device__ __forceinline__ u16 f2bf(float f) {
  unsigned u = __builtin_bit_cast(unsigned, f);
  u = (u + 0x7fffu + ((u >> 16) & 1u)) >> 16;   // round-to-nearest-even
  return (u16)u;
}
__device__ __forceinline__ float bf2f(u16 v) {
  unsigned u = ((unsigned)v) << 16;
  return __builtin_bit_cast(float, u);
}

// ---------------------------------------------------------------------------
// phase 0: c[h] = b2[h] + sum_d b1[h,d]*w2[h,d]      grid 128 x 256
// ---------------------------------------------------------------------------
__global__ __launch_bounds__(256)
void nlm_p0(const float* __restrict__ b1, const float* __restrict__ w2,
            const float* __restrict__ b2, float* __restrict__ ch) {
  const int h = blockIdx.x, t = threadIdx.x;
  const float4* pb = (const float4*)(b1 + (size_t)h * D_TOT);
  const float4* pw = (const float4*)(w2 + (size_t)h * D_TOT);
  float s = 0.f;
  for (int i = t; i < D_TOT / 4; i += 256) {
    float4 a = pb[i], w = pw[i];
    s += a.x * w.x + a.y * w.y + a.z * w.z + a.w * w.w;
  }
  __shared__ float red[256];
  red[t] = s;
  __syncthreads();
  for (int off = 128; off > 0; off >>= 1) {
    if (t < off) red[t] += red[t + off];
    __syncthreads();
  }
  if (t == 0) ch[h] = red[0] + b2[h];
}

// ---------------------------------------------------------------------------
// phase 1: partial[b][g][h] = sum over d-slice g (8 d's, all 64 m) of
//          x[b,d,m] * (w1[m,h,d]*w2[h,d]), bf16 MFMA, bf16 partial out.
// grid 512, block 512 (8 waves as 2x4).
// XCD swizzle: blockIdx = j*64 + group; g = group*4 + (j&3), bh = j>>2.
// All 8 WGs touching one 128B w1-line region (4 d-slices x 2 b-halves)
// share blockIdx%8 -> same XCD -> w1 line fetched from HBM ~once.
// ---------------------------------------------------------------------------
__global__ __launch_bounds__(512, 4)
void nlm_p1(const float* __restrict__ x, const float* __restrict__ w1,
            const float* __restrict__ w2, u16* __restrict__ partial) {
  __shared__ __align__(16) u16 As[128 * 72];
  __shared__ __align__(16) u16 Bs[128 * 72];

  const int tid  = threadIdx.x;
  const int grp  = blockIdx.x & 63;
  const int jj   = blockIdx.x >> 6;   // 0..7
  const int g    = grp * 4 + (jj & 3);
  const int bh   = jj >> 2;
  const int d0   = g * 8;
  const int lane = tid & 63, wave = tid >> 6;
  const int wm   = wave >> 2;         // 0..1 : 64-row b tile
  const int wn   = wave & 3;          // 0..3 : 32-col h tile
  const int quad = lane >> 4, l16 = lane & 15;

  // A staging task: thread -> (local b row, m4 in {0,1}, dj in {0,4})
  const int a_b  = tid >> 2;
  const int a_r  = tid & 3;
  const int a_m4 = a_r >> 1;
  const int a_j  = (a_r & 1) * 4;
  const float* xbase = x + (size_t)(bh * 128 + a_b) * XB
                         + (size_t)(d0 + a_j) * M_TOT + a_m4 * 4;

  // B staging task: thread -> (h, ml0) ; second task ml0+4, same h
  const int b_h   = tid & 127;
  const int b_ml0 = tid >> 7;         // 0..3
  const float* w2p = w2 + (size_t)b_h * D_TOT + d0;
  const float4 s0 = *(const float4*)(w2p);       // w2[h][d0..d0+4)
  const float4 s1 = *(const float4*)(w2p + 4);   // w2[h][d0+4..d0+8)

  f32x4 acc[4][2];
#pragma unroll
  for (int i = 0; i < 4; ++i)
#pragma unroll
    for (int j = 0; j < 2; ++j) acc[i][j] = (f32x4){0.f, 0.f, 0.f, 0.f};

  for (int c = 0; c < 8; ++c) {       // chunk = 8 m values
    { // ---- stage A: transpose 4d x 4m in registers, write k-contiguous
      const float* xp = xbase + c * 8;
      float4 v0 = *(const float4*)(xp);
      float4 v1 = *(const float4*)(xp + M_TOT);
      float4 v2 = *(const float4*)(xp + 2 * M_TOT);
      float4 v3 = *(const float4*)(xp + 3 * M_TOT);
      u16* ap = As + a_b * 72 + a_m4 * 32 + a_j;  // k = m_l*8 + d_l
      *(ushort4*)(ap)      = make_ushort4(f2bf(v0.x), f2bf(v1.x), f2bf(v2.x), f2bf(v3.x));
      *(ushort4*)(ap + 8)  = make_ushort4(f2bf(v0.y), f2bf(v1.y), f2bf(v2.y), f2bf(v3.y));
      *(ushort4*)(ap + 16) = make_ushort4(f2bf(v0.z), f2bf(v1.z), f2bf(v2.z), f2bf(v3.z));
      *(ushort4*)(ap + 24) = make_ushort4(f2bf(v0.w), f2bf(v1.w), f2bf(v2.w), f2bf(v3.w));
    }
    // ---- stage B: fused w1*w2, contiguous 8-d runs (32B from w1 per pair)
#pragma unroll
    for (int i = 0; i < 2; ++i) {
      const int ml = b_ml0 + i * 4;
      const float* w1p = w1 + (size_t)(c * 8 + ml) * W1M + (size_t)b_h * D_TOT + d0;
      float4 a0 = *(const float4*)(w1p);
      float4 a1 = *(const float4*)(w1p + 4);
      u16* bp = Bs + b_h * 72 + ml * 8;
      *(ushort4*)(bp)     = make_ushort4(f2bf(a0.x * s0.x), f2bf(a0.y * s0.y),
                                         f2bf(a0.z * s0.z), f2bf(a0.w * s0.w));
      *(ushort4*)(bp + 4) = make_ushort4(f2bf(a1.x * s1.x), f2bf(a1.y * s1.y),
                                         f2bf(a1.z * s1.z), f2bf(a1.w * s1.w));
    }
    __syncthreads();
    // ---- compute: 2 K-steps of 32, 8 MFMAs each
#pragma unroll
    for (int s = 0; s < 2; ++s) {
      short8 af[4], bq[2];
#pragma unroll
      for (int i = 0; i < 4; ++i)
        af[i] = *(const short8*)(As + (wm * 64 + i * 16 + l16) * 72 + s * 32 + quad * 8);
#pragma unroll
      for (int j = 0; j < 2; ++j)
        bq[j] = *(const short8*)(Bs + (wn * 32 + j * 16 + l16) * 72 + s * 32 + quad * 8);
#pragma unroll
      for (int i = 0; i < 4; ++i)
#pragma unroll
        for (int j = 0; j < 2; ++j)
          acc[i][j] = __builtin_amdgcn_mfma_f32_16x16x32_bf16(af[i], bq[j], acc[i][j], 0, 0, 0);
    }
    __syncthreads();
  }

  // ---- epilogue: bf16 partials, layout [b][g][h] (p2 streams contiguously)
  // C/D layout: col=lane&15, row=quad*4+reg
#pragma unroll
  for (int i = 0; i < 4; ++i)
#pragma unroll
    for (int j = 0; j < 2; ++j) {
      const int hcol = wn * 32 + j * 16 + l16;
#pragma unroll
      for (int r = 0; r < 4; ++r) {
        const int brow = bh * 128 + wm * 64 + i * 16 + quad * 4 + r;
        __builtin_nontemporal_store(
            f2bf(acc[i][j][r]),
            partial + ((size_t)brow * NG + g) * H_TOT + hcol);
      }
    }
}

// ---------------------------------------------------------------------------
// phase 2: out[b,h] = sum_g partial[b][g][h] + c[h]     grid 256 x 256
// each block streams its 64 KB of partial fully contiguously
// ---------------------------------------------------------------------------
__global__ __launch_bounds__(256)
void nlm_p2(const u16* __restrict__ partial, const float* __restrict__ ch,
            float* __restrict__ out) {
  const int b = blockIdx.x, t = threadIdx.x;
  const int h2   = t & 63;    // ushort2 column: h = 2*h2, 2*h2+1
  const int half = t >> 6;    // 0..3 : g range
  const u16* base = partial + ((size_t)b * NG + half * 64) * H_TOT + 2 * h2;
  float s0 = 0.f, s1 = 0.f;
#pragma unroll 8
  for (int gg = 0; gg < 64; ++gg) {
    unsigned v = __builtin_nontemporal_load((const unsigned*)(base + (size_t)gg * H_TOT));
    s0 += bf2f((u16)(v & 0xffffu));
    s1 += bf2f((u16)(v >> 16));
  }
  __shared__ float red0[256], red1[256];
  red0[t] = s0;
  red1[t] = s1;
  __syncthreads();
  if (t < 64) {
    float a0 = red0[t] + red0[t + 64] + red0[t + 128] + red0[t + 192];
    float a1 = red1[t] + red1[t + 64] + red1[t + 128] + red1[t + 192];
    out[(size_t)b * H_TOT + 2 * t]     = a0 + ch[2 * t];
    out[(size_t)b * H_TOT + 2 * t + 1] = a1 + ch[2 * t + 1];
  }
}

// ---------------------------------------------------------------------------
extern "C" void kernel_launch(void* const* d_in, const int* in_sizes, int n_in,
                              void* d_out, int out_size, void* d_ws, size_t ws_size,
                              hipStream_t stream) {
  const float* x  = (const float*)d_in[0];
  const float* w1 = (const float*)d_in[1];
  const float* b1 = (const float*)d_in[2];
  const float* w2 = (const float*)d_in[3];
  const float* b2 = (const float*)d_in[4];
  float* out = (float*)d_out;

  u16*   partial = (u16*)d_ws;                       // 256*256*128 bf16 = 16.78 MB
  float* ch      = (float*)((char*)d_ws + (size_t)B_TOT * NG * H_TOT * sizeof(u16));

  nlm_p0<<<dim3(128), dim3(256), 0, stream>>>(b1, w2, b2, ch);
  nlm_p1<<<dim3(512), dim3(512), 0, stream>>>(x, w1, w2, partial);
  nlm_p2<<<dim3(256), dim3(256), 0, stream>>>(partial, ch, out);
}

// Round 3
// 266.832 us; speedup vs baseline: 1.3487x; 1.1565x over previous
//
#include <hip/hip_runtime.h>

typedef unsigned short u16;
typedef __attribute__((ext_vector_type(8))) short short8;
typedef __attribute__((ext_vector_type(4))) float f32x4;

#define D_TOT 2048
#define M_TOT 64
#define H_TOT 128
#define B_TOT 256
#define NG    256      /* number of d-slices (each 8 d's) */
#define XB    131072   /* D_TOT*M_TOT : x row stride per b */
#define W1M   262144   /* H_TOT*D_TOT : w1 stride per m */

__device__ __forceinline__ u16 f2bf(float f) {
  unsigned u = __builtin_bit_cast(unsigned, f);
  u = (u + 0x7fffu + ((u >> 16) & 1u)) >> 16;   // round-to-nearest-even
  return (u16)u;
}
__device__ __forceinline__ float bf2f(u16 v) {
  unsigned u = ((unsigned)v) << 16;
  return __builtin_bit_cast(float, u);
}

// ---------------------------------------------------------------------------
// phase 0: c[h] = b2[h] + sum_d b1[h,d]*w2[h,d]      grid 128 x 256
// ---------------------------------------------------------------------------
__global__ __launch_bounds__(256)
void nlm_p0(const float* __restrict__ b1, const float* __restrict__ w2,
            const float* __restrict__ b2, float* __restrict__ ch) {
  const int h = blockIdx.x, t = threadIdx.x;
  const float4* pb = (const float4*)(b1 + (size_t)h * D_TOT);
  const float4* pw = (const float4*)(w2 + (size_t)h * D_TOT);
  float s = 0.f;
  for (int i = t; i < D_TOT / 4; i += 256) {
    float4 a = pb[i], w = pw[i];
    s += a.x * w.x + a.y * w.y + a.z * w.z + a.w * w.w;
  }
  __shared__ float red[256];
  red[t] = s;
  __syncthreads();
  for (int off = 128; off > 0; off >>= 1) {
    if (t < off) red[t] += red[t + off];
    __syncthreads();
  }
  if (t == 0) ch[h] = red[0] + b2[h];
}

// ---------------------------------------------------------------------------
// pw: pre-pack B'[g][c][h][m] = bf16( w1[m][h][g*8+c] * w2[h][g*8+c] ).
// Reads w1 in FULL 128-B d-runs (exact 67 MB), writes 33.5 MB streaming.
// grid 512 = 64 g-quads (32 d) x 8 h-blocks (16 h), block 256.
// ---------------------------------------------------------------------------
__global__ __launch_bounds__(256)
void nlm_pw(const float* __restrict__ w1, const float* __restrict__ w2,
            u16* __restrict__ Bp) {
  const int gq  = blockIdx.x & 63;
  const int hb  = blockIdx.x >> 6;
  const int dq0 = gq * 32;
  const int t   = threadIdx.x;
  __shared__ u16 tile[32 * 16 * 64];  // [dc][h_l][m] = 64 KB

  // 1024 tasks: tau = h_l*64 + m  (wave => uniform h, m=lane: w2 wave-uniform,
  // LDS b16 writes 2-way conflict only)
#pragma unroll
  for (int rep = 0; rep < 4; ++rep) {
    const int tau = rep * 256 + t;
    const int h_l = tau >> 6, m = tau & 63;
    const int h   = hb * 16 + h_l;
    const float* w1p = w1 + (size_t)m * W1M + (size_t)h * D_TOT + dq0;
    const float* w2p = w2 + (size_t)h * D_TOT + dq0;
    u16* dst = tile + h_l * 64 + m;   // + dc*1024
#pragma unroll
    for (int q = 0; q < 8; ++q) {      // 8 x float4 = the full 128-B line
      float4 a = *(const float4*)(w1p + q * 4);
      float4 s = *(const float4*)(w2p + q * 4);
      dst[(q * 4 + 0) * 1024] = f2bf(a.x * s.x);
      dst[(q * 4 + 1) * 1024] = f2bf(a.y * s.y);
      dst[(q * 4 + 2) * 1024] = f2bf(a.z * s.z);
      dst[(q * 4 + 3) * 1024] = f2bf(a.w * s.w);
    }
  }
  __syncthreads();
  // write out 32 contiguous 2-KB segments (one per dc)
#pragma unroll 4
  for (int dc = 0; dc < 32; ++dc) {
    const int g = gq * 4 + (dc >> 3), c = dc & 7;
    u16* out = Bp + (((size_t)g * 8 + c) * H_TOT + hb * 16) * 64 + t * 4;
    *(ushort4*)out = *(const ushort4*)(tile + dc * 1024 + t * 4);
  }
}

// ---------------------------------------------------------------------------
// phase 1: partial[b][g][h] += x * B', K-order = d-major/m-minor.
// chunk c = single d, all 64 m: A-stage = full 256-B x rows, exact-once.
// grid 1024 = 4 b-quarters x 256 g; blockIdx%8 = g%8 -> bq-sharers co-XCD.
// block 512 = 8 waves as 2(bm) x 4(hn); per-wave tile 32b x 32h.
// ---------------------------------------------------------------------------
__global__ __launch_bounds__(512, 4)
void nlm_p1(const float* __restrict__ x, const u16* __restrict__ Bp,
            u16* __restrict__ partial) {
  __shared__ __align__(16) u16 As[64 * 72];    // row b_l, 64 m + 8 pad
  __shared__ __align__(16) u16 Bs[128 * 72];   // row h,   64 m + 8 pad

  const int tid  = threadIdx.x;
  const int g    = blockIdx.x & 255;
  const int bq   = blockIdx.x >> 8;
  const int d0   = g * 8;
  const int lane = tid & 63, wave = tid >> 6;
  const int wm   = wave >> 2;         // 0..1
  const int wn   = wave & 3;          // 0..3
  const int quad = lane >> 4, l16 = lane & 15;

  // A staging: thread -> (b_l = tid>>3, part = tid&7): 32 B of one x row
  const int a_bl = tid >> 3, a_p = tid & 7;
  const float* xrow = x + (size_t)(bq * 64 + a_bl) * XB
                        + (size_t)d0 * M_TOT + a_p * 8;
  // B staging: thread -> (h = tid>>2, qp = tid&3): 32 B of B' chunk
  const int b_h = tid >> 2, b_qp = tid & 3;
  const u16* bsrc = Bp + ((size_t)g * 8 * H_TOT + b_h) * 64 + b_qp * 16;

  f32x4 acc[2][2];
#pragma unroll
  for (int i = 0; i < 2; ++i)
#pragma unroll
    for (int j = 0; j < 2; ++j) acc[i][j] = (f32x4){0.f, 0.f, 0.f, 0.f};

  for (int c = 0; c < 8; ++c) {
    { // ---- stage A: 8 consecutive m of one (b, d=d0+c) row, m-contiguous
      const float* xp = xrow + c * M_TOT;
      float4 v0 = *(const float4*)(xp);
      float4 v1 = *(const float4*)(xp + 4);
      short8 av;
      av[0] = (short)f2bf(v0.x); av[1] = (short)f2bf(v0.y);
      av[2] = (short)f2bf(v0.z); av[3] = (short)f2bf(v0.w);
      av[4] = (short)f2bf(v1.x); av[5] = (short)f2bf(v1.y);
      av[6] = (short)f2bf(v1.z); av[7] = (short)f2bf(v1.w);
      *(short8*)(As + a_bl * 72 + a_p * 8) = av;
    }
    { // ---- stage B: 32 B contiguous from pre-packed B'
      const u16* bp = bsrc + (size_t)c * (H_TOT * 64);
      *(short8*)(Bs + b_h * 72 + b_qp * 16)     = *(const short8*)(bp);
      *(short8*)(Bs + b_h * 72 + b_qp * 16 + 8) = *(const short8*)(bp + 8);
    }
    __syncthreads();
#pragma unroll
    for (int s = 0; s < 2; ++s) {
      short8 af[2], bf[2];
#pragma unroll
      for (int i = 0; i < 2; ++i)
        af[i] = *(const short8*)(As + (wm * 32 + i * 16 + l16) * 72 + s * 32 + quad * 8);
#pragma unroll
      for (int j = 0; j < 2; ++j)
        bf[j] = *(const short8*)(Bs + (wn * 32 + j * 16 + l16) * 72 + s * 32 + quad * 8);
#pragma unroll
      for (int i = 0; i < 2; ++i)
#pragma unroll
        for (int j = 0; j < 2; ++j)
          acc[i][j] = __builtin_amdgcn_mfma_f32_16x16x32_bf16(af[i], bf[j], acc[i][j], 0, 0, 0);
    }
    __syncthreads();
  }

  // ---- epilogue: bf16 partials [b][g][h]; plain stores (waves wn 0..3
  // cover full 256-B h-rows -> L2 write-combines full lines)
#pragma unroll
  for (int i = 0; i < 2; ++i)
#pragma unroll
    for (int j = 0; j < 2; ++j) {
      const int hcol = wn * 32 + j * 16 + l16;
#pragma unroll
      for (int r = 0; r < 4; ++r) {
        const int brow = bq * 64 + wm * 32 + i * 16 + quad * 4 + r;
        partial[((size_t)brow * NG + g) * H_TOT + hcol] = f2bf(acc[i][j][r]);
      }
    }
}

// ---------------------------------------------------------------------------
// phase 2: out[b,h] = sum_g partial[b][g][h] + c[h]     grid 256 x 256
// ---------------------------------------------------------------------------
__global__ __launch_bounds__(256)
void nlm_p2(const u16* __restrict__ partial, const float* __restrict__ ch,
            float* __restrict__ out) {
  const int b = blockIdx.x, t = threadIdx.x;
  const int h2   = t & 63;    // ushort2 column: h = 2*h2, 2*h2+1
  const int half = t >> 6;    // 0..3 : g range
  const u16* base = partial + ((size_t)b * NG + half * 64) * H_TOT + 2 * h2;
  float s0 = 0.f, s1 = 0.f;
#pragma unroll 8
  for (int gg = 0; gg < 64; ++gg) {
    unsigned v = __builtin_nontemporal_load((const unsigned*)(base + (size_t)gg * H_TOT));
    s0 += bf2f((u16)(v & 0xffffu));
    s1 += bf2f((u16)(v >> 16));
  }
  __shared__ float red0[256], red1[256];
  red0[t] = s0;
  red1[t] = s1;
  __syncthreads();
  if (t < 64) {
    float a0 = red0[t] + red0[t + 64] + red0[t + 128] + red0[t + 192];
    float a1 = red1[t] + red1[t + 64] + red1[t + 128] + red1[t + 192];
    out[(size_t)b * H_TOT + 2 * t]     = a0 + ch[2 * t];
    out[(size_t)b * H_TOT + 2 * t + 1] = a1 + ch[2 * t + 1];
  }
}

// ---------------------------------------------------------------------------
extern "C" void kernel_launch(void* const* d_in, const int* in_sizes, int n_in,
                              void* d_out, int out_size, void* d_ws, size_t ws_size,
                              hipStream_t stream) {
  const float* x  = (const float*)d_in[0];
  const float* w1 = (const float*)d_in[1];
  const float* b1 = (const float*)d_in[2];
  const float* w2 = (const float*)d_in[3];
  const float* b2 = (const float*)d_in[4];
  float* out = (float*)d_out;

  // ws: partial 16.78 MB | B' 33.55 MB | ch 512 B   (needs ~50.4 MB)
  u16*   partial = (u16*)d_ws;
  u16*   Bp      = (u16*)((char*)d_ws + (size_t)B_TOT * NG * H_TOT * sizeof(u16));
  float* ch      = (float*)((char*)d_ws + (size_t)B_TOT * NG * H_TOT * sizeof(u16)
                                        + (size_t)NG * 8 * H_TOT * 64 * sizeof(u16));

  nlm_p0<<<dim3(128),  dim3(256), 0, stream>>>(b1, w2, b2, ch);
  nlm_pw<<<dim3(512),  dim3(256), 0, stream>>>(w1, w2, Bp);
  nlm_p1<<<dim3(1024), dim3(512), 0, stream>>>(x, Bp, partial);
  nlm_p2<<<dim3(256),  dim3(256), 0, stream>>>(partial, ch, out);
}